// Round 1
// baseline (574.023 us; speedup 1.0000x reference)
//
#include <hip/hip_runtime.h>

// CRF loss: mean over batch of (logZ - path_score).
// B=512, T=1024, K=48.
// Strategy: one wave (64 threads) per sequence. Linear-domain scaled forward
// algorithm: p_t = normalize( (expT @ p_{t-1}) * exp(E_t) ), log-scale in c.
// Lane i owns dest tag i; expT row i and a replicated copy of p live in VGPRs;
// new state broadcast each step via ping-pong LDS buffer.

#define BB 512
#define TT 1024
#define KK 48

__device__ __forceinline__ float wave_reduce_max(float v) {
    #pragma unroll
    for (int off = 32; off > 0; off >>= 1)
        v = fmaxf(v, __shfl_xor(v, off, 64));
    return v;
}

__device__ __forceinline__ float wave_reduce_sum(float v) {
    #pragma unroll
    for (int off = 32; off > 0; off >>= 1)
        v += __shfl_xor(v, off, 64);
    return v;
}

__global__ __launch_bounds__(64) void crf_forward_kernel(
    const float* __restrict__ emis,    // [B,T,K]
    const int*   __restrict__ lengths, // [B]
    const int*   __restrict__ tags,    // [B,T]
    const float* __restrict__ prior,   // [K]
    const float* __restrict__ trans,   // [K,K]  trans[dest][src]
    const float* __restrict__ finalT,  // [K]
    float*       __restrict__ out_per_b) // [B] workspace
{
    const int b    = blockIdx.x;
    const int lane = threadIdx.x;
    const bool act = lane < KK;
    const int i    = act ? lane : (KK - 1);   // clamp idle lanes to safe row

    int len = lengths[b];
    if (len < 1) len = 1;
    if (len > TT) len = TT;

    __shared__ __align__(16) float pbuf[2][64];

    // ---- exp(transition) row i -> registers (12 x float4, 16B-aligned) ----
    float4 Trow[12];
    #pragma unroll
    for (int j = 0; j < 12; ++j) {
        float4 t4 = reinterpret_cast<const float4*>(trans + i * KK)[j];
        Trow[j].x = __expf(t4.x);
        Trow[j].y = __expf(t4.y);
        Trow[j].z = __expf(t4.z);
        Trow[j].w = __expf(t4.w);
    }

    const float* eb = emis + (size_t)b * TT * KK;

    // ---- init: alpha0 = E[:,0,:] + prior, kept as p = exp(alpha0 - m0), c = m0
    float a0 = eb[i] + prior[i];
    float m0 = wave_reduce_max(act ? a0 : -3.0e38f);
    float q  = act ? __expf(a0 - m0) : 0.0f;   // this lane's own state entry
    float c  = m0;                              // running log-scale (uniform)

    if (act) pbuf[0][lane] = q;
    __syncthreads();

    float4 p[12];
    #pragma unroll
    for (int j = 0; j < 12; ++j)
        p[j] = reinterpret_cast<const float4*>(pbuf[0])[j];

    float eNext = eb[KK + i];   // emission for t=1 (T>=2 always)

    for (int t = 1; t < len; ++t) {
        float e = eNext;
        int tn = (t + 1 < len) ? (t + 1) : (len - 1);
        eNext = eb[(size_t)tn * KK + i];        // prefetch next emission

        // q[i] = sum_j expT[i][j] * p[j]   (4 independent partial chains)
        float s0 = 0.f, s1 = 0.f, s2 = 0.f, s3 = 0.f;
        #pragma unroll
        for (int j = 0; j < 12; ++j) {
            s0 = fmaf(Trow[j].x, p[j].x, s0);
            s1 = fmaf(Trow[j].y, p[j].y, s1);
            s2 = fmaf(Trow[j].z, p[j].z, s2);
            s3 = fmaf(Trow[j].w, p[j].w, s3);
        }
        float s = (s0 + s1) + (s2 + s3);
        q = s * __expf(e);
        if (!act) q = 0.0f;

        // rescale every 4 steps: keeps fp32 in range; bookkeeping in c
        if ((t & 3) == 0) {
            float m = wave_reduce_max(q);       // > 0 always
            c += __logf(m);
            q *= (1.0f / m);
        }

        // broadcast new state via ping-pong LDS (WAR-safe: alternating bufs)
        float* buf = pbuf[t & 1];
        if (act) buf[lane] = q;
        __syncthreads();
        #pragma unroll
        for (int j = 0; j < 12; ++j)
            p[j] = reinterpret_cast<const float4*>(buf)[j];
    }

    // ---- logZ = c + log( sum_i p[i] * exp(finalT[i]) )  (lane's own q) ----
    float fv = act ? q * __expf(finalT[i]) : 0.0f;
    float S  = wave_reduce_sum(fv);
    float logZ = c + __logf(S);

    // ---- path score (gathers, ~len/64 iterations per wave) ----
    float ps = 0.0f;
    const int* tg = tags + (size_t)b * TT;
    for (int t = lane; t < len; t += 64) {
        int cur = tg[t];
        float ev = eb[(size_t)t * KK + cur];
        float tr = (t == 0) ? prior[cur] : trans[cur * KK + tg[t - 1]];
        ps += ev + tr;
    }
    ps = wave_reduce_sum(ps);
    float fin = finalT[tg[len - 1]];

    if (lane == 0) out_per_b[b] = logZ - (ps + fin);
}

__global__ __launch_bounds__(512) void reduce_mean_kernel(
    const float* __restrict__ v, float* __restrict__ out)
{
    __shared__ float sm[8];
    int tid = threadIdx.x;          // 512 threads = 8 waves
    float x = v[tid];
    x = wave_reduce_sum(x);
    if ((tid & 63) == 0) sm[tid >> 6] = x;
    __syncthreads();
    if (tid < 8) {
        float y = sm[tid];
        y += __shfl_xor(y, 1, 64);
        y += __shfl_xor(y, 2, 64);
        y += __shfl_xor(y, 4, 64);
        if (tid == 0) out[0] = y * (1.0f / 512.0f);
    }
}

extern "C" void kernel_launch(void* const* d_in, const int* in_sizes, int n_in,
                              void* d_out, int out_size, void* d_ws, size_t ws_size,
                              hipStream_t stream) {
    const float* emis    = (const float*)d_in[0];
    const int*   lengths = (const int*)  d_in[1];
    const int*   tags    = (const int*)  d_in[2];
    const float* prior   = (const float*)d_in[3];
    const float* trans   = (const float*)d_in[4];
    const float* finalT  = (const float*)d_in[5];

    float* ws  = (float*)d_ws;      // 512 floats of per-sequence results
    float* out = (float*)d_out;

    crf_forward_kernel<<<BB, 64, 0, stream>>>(emis, lengths, tags, prior,
                                              trans, finalT, ws);
    reduce_mean_kernel<<<1, 512, 0, stream>>>(ws, out);
}

// Round 2
// 540.579 us; speedup vs baseline: 1.0619x; 1.0619x over previous
//
#include <hip/hip_runtime.h>

// CRF loss: mean over batch of (logZ - path_score).  B=512, T=1024, K=48.
// One wave (64 threads) per sequence. Scaled linear-domain forward:
//   p_t = (expT @ p_{t-1}) * exp(E_t), running log-scale c, rescale every 8 steps.
// Lane i owns dest tag i. The state broadcast uses v_readlane (VALU, in-wave,
// no LDS / no barrier): q_i = sum_j Trow[j] * readlane(q, j).
// Lanes 48..63 are clamped to row 47 and compute an exact duplicate of lane 47,
// so no per-step masking is needed; only the final sum masks them out.

#define BB 512
#define TT 1024
#define KK 48

__device__ __forceinline__ float wave_reduce_max(float v) {
    #pragma unroll
    for (int off = 32; off > 0; off >>= 1)
        v = fmaxf(v, __shfl_xor(v, off, 64));
    return v;
}

__device__ __forceinline__ float wave_reduce_sum(float v) {
    #pragma unroll
    for (int off = 32; off > 0; off >>= 1)
        v += __shfl_xor(v, off, 64);
    return v;
}

__device__ __forceinline__ float readlane_f(float v, int l) {
    return __int_as_float(__builtin_amdgcn_readlane(__float_as_int(v), l));
}

__global__ __launch_bounds__(64) void crf_forward_kernel(
    const float* __restrict__ emis,    // [B,T,K]
    const int*   __restrict__ lengths, // [B]
    const int*   __restrict__ tags,    // [B,T]
    const float* __restrict__ prior,   // [K]
    const float* __restrict__ trans,   // [K,K]  trans[dest][src]
    const float* __restrict__ finalT,  // [K]
    float*       __restrict__ out_per_b) // [B] workspace
{
    const int b    = blockIdx.x;
    const int lane = threadIdx.x;
    const bool act = lane < KK;
    const int i    = act ? lane : (KK - 1);   // idle lanes duplicate row 47

    int len = lengths[b];
    if (len < 1) len = 1;
    if (len > TT) len = TT;

    // ---- exp(transition) row i -> 48 registers ----
    float Trow[KK];
    {
        const float4* tr4 = reinterpret_cast<const float4*>(trans + i * KK);
        #pragma unroll
        for (int j = 0; j < 12; ++j) {
            float4 t4 = tr4[j];
            Trow[4*j+0] = __expf(t4.x);
            Trow[4*j+1] = __expf(t4.y);
            Trow[4*j+2] = __expf(t4.z);
            Trow[4*j+3] = __expf(t4.w);
        }
    }

    const float* eb = emis + (size_t)b * TT * KK;

    // ---- init: alpha0 = E[:,0,:] + prior;  p = exp(alpha0 - m0), c = m0 ----
    float a0 = eb[i] + prior[i];
    float m0 = wave_reduce_max(a0);           // idle lanes duplicate a0[47]
    float q  = __expf(a0 - m0);               // this lane's state entry
    float c  = m0;                            // running log-scale

    // ---- emission prefetch pipeline (depth 2) ----
    int t1 = (len > 1) ? 1 : 0;
    int t2 = (len > 2) ? 2 : (len - 1);
    float eN1 = eb[(size_t)t1 * KK + i];
    float eN2 = eb[(size_t)t2 * KK + i];

    for (int t = 1; t < len; ++t) {
        float e = eN1;
        eN1 = eN2;
        int tp = t + 2;
        if (tp > len - 1) tp = len - 1;
        eN2 = eb[(size_t)tp * KK + i];

        float expe = __expf(e);               // overlaps the FMA chain

        // q_new[i] = sum_j Trow[j] * q[j] : readlane broadcast, 4 acc chains
        float s0 = 0.f, s1 = 0.f, s2 = 0.f, s3 = 0.f;
        #pragma unroll
        for (int j = 0; j < KK; j += 4) {
            s0 = fmaf(Trow[j+0], readlane_f(q, j+0), s0);
            s1 = fmaf(Trow[j+1], readlane_f(q, j+1), s1);
            s2 = fmaf(Trow[j+2], readlane_f(q, j+2), s2);
            s3 = fmaf(Trow[j+3], readlane_f(q, j+3), s3);
        }
        q = ((s0 + s1) + (s2 + s3)) * expe;

        // rescale every 8 steps: growth/step <= ~2e4 -> 8 steps < 1e35, safe
        if ((t & 7) == 0) {
            float m = wave_reduce_max(q);     // > 0 always
            c += __logf(m);
            q *= (1.0f / m);
        }
    }

    // ---- logZ = c + log( sum_i q_i * exp(finalT_i) ) ----
    float fv = act ? q * __expf(finalT[i]) : 0.0f;   // mask duplicate lanes
    float S  = wave_reduce_sum(fv);
    float logZ = c + __logf(S);

    // ---- path score (gathers, ~len/64 iterations per wave) ----
    float ps = 0.0f;
    const int* tg = tags + (size_t)b * TT;
    for (int t = lane; t < len; t += 64) {
        int cur = tg[t];
        float ev = eb[(size_t)t * KK + cur];
        float tr = (t == 0) ? prior[cur] : trans[cur * KK + tg[t - 1]];
        ps += ev + tr;
    }
    ps = wave_reduce_sum(ps);
    float fin = finalT[tg[len - 1]];

    if (lane == 0) out_per_b[b] = logZ - (ps + fin);
}

__global__ __launch_bounds__(512) void reduce_mean_kernel(
    const float* __restrict__ v, float* __restrict__ out)
{
    __shared__ float sm[8];
    int tid = threadIdx.x;          // 512 threads = 8 waves
    float x = v[tid];
    x = wave_reduce_sum(x);
    if ((tid & 63) == 0) sm[tid >> 6] = x;
    __syncthreads();
    if (tid < 8) {
        float y = sm[tid];
        y += __shfl_xor(y, 1, 64);
        y += __shfl_xor(y, 2, 64);
        y += __shfl_xor(y, 4, 64);
        if (tid == 0) out[0] = y * (1.0f / 512.0f);
    }
}

extern "C" void kernel_launch(void* const* d_in, const int* in_sizes, int n_in,
                              void* d_out, int out_size, void* d_ws, size_t ws_size,
                              hipStream_t stream) {
    const float* emis    = (const float*)d_in[0];
    const int*   lengths = (const int*)  d_in[1];
    const int*   tags    = (const int*)  d_in[2];
    const float* prior   = (const float*)d_in[3];
    const float* trans   = (const float*)d_in[4];
    const float* finalT  = (const float*)d_in[5];

    float* ws  = (float*)d_ws;      // 512 floats of per-sequence results
    float* out = (float*)d_out;

    crf_forward_kernel<<<BB, 64, 0, stream>>>(emis, lengths, tags, prior,
                                              trans, finalT, ws);
    reduce_mean_kernel<<<1, 512, 0, stream>>>(ws, out);
}

// Round 3
// 386.558 us; speedup vs baseline: 1.4850x; 1.3984x over previous
//
#include <hip/hip_runtime.h>

// CRF loss: mean over batch of (logZ - path_score).  B=512, T=1024, K=48.
// One wave (64 threads) per sequence. Scaled linear-domain forward:
//   p_t = (expT @ p_{t-1}) * exp(E_t), running log-scale c, rescale every 8.
// Lane i owns dest tag i; expT row i lives in 48 VGPRs (launch_bounds(64,1)
// unlocks the 256-VGPR budget — with the default bounds the RA demoted the
// row to scratch, which was the ~990 cyc/step bottleneck in rounds 1-2).
// State broadcast via v_readlane (in-wave, no LDS, no barrier).
// Lanes 48..63 duplicate row 47; masked out only in the final sum.
// Emission loads are software-pipelined 4 steps deep (named regs, 4x unroll)
// to cover ~900-cycle HBM-miss latency.

#define BB 512
#define TT 1024
#define KK 48

__device__ __forceinline__ float wave_reduce_max(float v) {
    #pragma unroll
    for (int off = 32; off > 0; off >>= 1)
        v = fmaxf(v, __shfl_xor(v, off, 64));
    return v;
}

__device__ __forceinline__ float wave_reduce_sum(float v) {
    #pragma unroll
    for (int off = 32; off > 0; off >>= 1)
        v += __shfl_xor(v, off, 64);
    return v;
}

__device__ __forceinline__ float readlane_f(float v, int l) {
    return __int_as_float(__builtin_amdgcn_readlane(__float_as_int(v), l));
}

__global__ __launch_bounds__(64, 1) void crf_forward_kernel(
    const float* __restrict__ emis,    // [B,T,K]
    const int*   __restrict__ lengths, // [B]
    const int*   __restrict__ tags,    // [B,T]
    const float* __restrict__ prior,   // [K]
    const float* __restrict__ trans,   // [K,K]  trans[dest][src]
    const float* __restrict__ finalT,  // [K]
    float*       __restrict__ out_per_b) // [B] workspace
{
    const int b    = blockIdx.x;
    const int lane = threadIdx.x;
    const bool act = lane < KK;
    const int i    = act ? lane : (KK - 1);   // idle lanes duplicate row 47

    int len = lengths[b];
    if (len < 1) len = 1;
    if (len > TT) len = TT;
    const int len1 = len - 1;

    // ---- exp(transition) row i -> 48 VGPRs ----
    float Trow[KK];
    {
        const float4* tr4 = reinterpret_cast<const float4*>(trans + i * KK);
        #pragma unroll
        for (int j = 0; j < 12; ++j) {
            float4 t4 = tr4[j];
            Trow[4*j+0] = __expf(t4.x);
            Trow[4*j+1] = __expf(t4.y);
            Trow[4*j+2] = __expf(t4.z);
            Trow[4*j+3] = __expf(t4.w);
        }
    }

    const float* eb = emis + (size_t)b * TT * KK;

    // ---- init: alpha0 = E[:,0,:] + prior;  q = exp(alpha0 - m0), c = m0 ----
    float a0 = eb[i] + prior[i];
    float m0 = wave_reduce_max(a0);           // idle lanes duplicate a0[47]
    float q  = __expf(a0 - m0);
    float c  = m0;                            // running log-scale

    // ---- emission software pipeline, depth 4 ----
    int t = 1;
    float ep0 = eb[(size_t)((1 <= len1) ? 1 : len1) * KK + i];
    float ep1 = eb[(size_t)((2 <= len1) ? 2 : len1) * KK + i];
    float ep2 = eb[(size_t)((3 <= len1) ? 3 : len1) * KK + i];
    float ep3 = eb[(size_t)((4 <= len1) ? 4 : len1) * KK + i];

#define CRF_STEP(EP)                                                      \
    {                                                                     \
        float e = EP;                                                     \
        int tp = t + 4; if (tp > len1) tp = len1;                         \
        EP = eb[(size_t)tp * KK + i];          /* refill, used t+4 */     \
        float expe = __expf(e);                                           \
        float s0 = 0.f, s1 = 0.f, s2 = 0.f, s3 = 0.f;                     \
        _Pragma("unroll")                                                 \
        for (int j = 0; j < KK; j += 4) {                                 \
            s0 = fmaf(Trow[j+0], readlane_f(q, j+0), s0);                 \
            s1 = fmaf(Trow[j+1], readlane_f(q, j+1), s1);                 \
            s2 = fmaf(Trow[j+2], readlane_f(q, j+2), s2);                 \
            s3 = fmaf(Trow[j+3], readlane_f(q, j+3), s3);                 \
        }                                                                 \
        q = ((s0 + s1) + (s2 + s3)) * expe;                               \
        if ((t & 7) == 0) {                                               \
            float m = wave_reduce_max(q);      /* > 0 always */           \
            c += __logf(m);                                               \
            q *= __builtin_amdgcn_rcpf(m);     /* log-compensated */      \
        }                                                                 \
        ++t;                                                              \
    }

    while (t < len) {
        CRF_STEP(ep0); if (t >= len) break;
        CRF_STEP(ep1); if (t >= len) break;
        CRF_STEP(ep2); if (t >= len) break;
        CRF_STEP(ep3);
    }
#undef CRF_STEP

    // ---- logZ = c + log( sum_i q_i * exp(finalT_i) ) ----
    float fv = act ? q * __expf(finalT[i]) : 0.0f;   // mask duplicate lanes
    float S  = wave_reduce_sum(fv);
    float logZ = c + __logf(S);

    // ---- path score (gathers, ~len/64 iterations per wave) ----
    float ps = 0.0f;
    const int* tg = tags + (size_t)b * TT;
    for (int tt = lane; tt < len; tt += 64) {
        int cur = tg[tt];
        float ev = eb[(size_t)tt * KK + cur];
        float tr = (tt == 0) ? prior[cur] : trans[cur * KK + tg[tt - 1]];
        ps += ev + tr;
    }
    ps = wave_reduce_sum(ps);
    float fin = finalT[tg[len1]];

    if (lane == 0) out_per_b[b] = logZ - (ps + fin);
}

__global__ __launch_bounds__(512) void reduce_mean_kernel(
    const float* __restrict__ v, float* __restrict__ out)
{
    __shared__ float sm[8];
    int tid = threadIdx.x;          // 512 threads = 8 waves
    float x = v[tid];
    x = wave_reduce_sum(x);
    if ((tid & 63) == 0) sm[tid >> 6] = x;
    __syncthreads();
    if (tid < 8) {
        float y = sm[tid];
        y += __shfl_xor(y, 1, 64);
        y += __shfl_xor(y, 2, 64);
        y += __shfl_xor(y, 4, 64);
        if (tid == 0) out[0] = y * (1.0f / 512.0f);
    }
}

extern "C" void kernel_launch(void* const* d_in, const int* in_sizes, int n_in,
                              void* d_out, int out_size, void* d_ws, size_t ws_size,
                              hipStream_t stream) {
    const float* emis    = (const float*)d_in[0];
    const int*   lengths = (const int*)  d_in[1];
    const int*   tags    = (const int*)  d_in[2];
    const float* prior   = (const float*)d_in[3];
    const float* trans   = (const float*)d_in[4];
    const float* finalT  = (const float*)d_in[5];

    float* ws  = (float*)d_ws;      // 512 floats of per-sequence results
    float* out = (float*)d_out;

    crf_forward_kernel<<<BB, 64, 0, stream>>>(emis, lengths, tags, prior,
                                              trans, finalT, ws);
    reduce_mean_kernel<<<1, 512, 0, stream>>>(ws, out);
}